// Round 1
// baseline (815.267 us; speedup 1.0000x reference)
//
#include <hip/hip_runtime.h>
#include <hip/hip_bf16.h>
#include <math.h>

// Problem constants (B,N,D,L fixed by setup_inputs)
#define BB 8
#define NN 2048
#define DD 128
#define LL 3
#define GN_EPS 1e-5f

// ---------------------------------------------------------------------------
// K1: degree / dinv.  dinv[b*N+i] = rsqrt( sum_j dist(i,j) + 1 )
// grid: B*8 blocks of 256; each thread owns one row i, coords staged in LDS.
// ---------------------------------------------------------------------------
__global__ __launch_bounds__(256)
void deg_kernel(const float* __restrict__ inst, float* __restrict__ dinv)
{
    __shared__ float cs[NN * 2];          // 16 KB: [n][2]
    const int b  = blockIdx.x >> 3;
    const int i0 = (blockIdx.x & 7) * 256;
    const int tid = threadIdx.x;
    const float* instb = inst + b * NN * 2;
    for (int k = tid; k < NN * 2; k += 256) cs[k] = instb[k];
    __syncthreads();
    const int i = i0 + tid;
    const float xi = cs[i * 2 + 0];
    const float yi = cs[i * 2 + 1];
    float acc = 0.f;
    #pragma unroll 8
    for (int j = 0; j < NN; ++j) {
        float dx = xi - cs[j * 2 + 0];
        float dy = yi - cs[j * 2 + 1];
        acc += sqrtf(dx * dx + dy * dy);   // j==i contributes exactly 0
    }
    dinv[b * NN + i] = rsqrtf(acc + 1.0f); // +1 self-loop
}

// ---------------------------------------------------------------------------
// K2: proj_node.  h[b,n,d] = x0*Wn[d,0] + x1*Wn[d,1] + bn[d]
// ---------------------------------------------------------------------------
__global__ __launch_bounds__(256)
void proj_kernel(const float* __restrict__ inst, const float* __restrict__ Wn,
                 const float* __restrict__ bn, float* __restrict__ h)
{
    const int idx = blockIdx.x * 256 + threadIdx.x;   // < B*N*D
    const int d   = idx & (DD - 1);
    const int row = idx >> 7;
    const float x0 = inst[row * 2 + 0];
    const float x1 = inst[row * 2 + 1];
    h[idx] = x0 * Wn[d * 2 + 0] + x1 * Wn[d * 2 + 1] + bn[d];
}

// ---------------------------------------------------------------------------
// K3: lin + dinv scale.  t[row,d] = dinv[row] * sum_e h[row,e] * Wg_l[d,e]
// GEMM M=B*N, N=128, K=128.  Block: 64 rows x 128 d, 256 threads,
// per-thread 4 rows x 8 d (two float4 halves at d and d+64).
// ---------------------------------------------------------------------------
__global__ __launch_bounds__(256)
void lin_kernel(const float* __restrict__ h, const float* __restrict__ Wg_l,
                const float* __restrict__ dinv, float* __restrict__ t)
{
    __shared__ float h_s[64][132];    // 33.8 KB
    __shared__ float wg_s[32][132];   // 16.9 KB  (e-chunk x d, transposed)
    const int tid  = threadIdx.x;
    const int row0 = blockIdx.x * 64;
    const int dg = tid & 15;          // d = dg*4 and dg*4+64
    const int rg = tid >> 4;          // rows rg*4 .. rg*4+3

    float acc[4][8];
    #pragma unroll
    for (int i = 0; i < 4; ++i)
        #pragma unroll
        for (int j = 0; j < 8; ++j) acc[i][j] = 0.f;

    // stage h tile: 64x128 floats, coalesced float4
    #pragma unroll
    for (int i = 0; i < 8; ++i) {
        int f = tid + i * 256;        // 0..2047 float4 slots
        int r = f >> 5;
        int c4 = f & 31;
        *(float4*)&h_s[r][c4 * 4] = *(const float4*)&h[(size_t)(row0 + r) * DD + c4 * 4];
    }

    for (int kc = 0; kc < 4; ++kc) {
        __syncthreads();
        // stage Wg chunk transposed: wg_s[e][d], e = kc*32 + ee
        #pragma unroll
        for (int i = 0; i < 4; ++i) {
            int f = tid + i * 256;    // 0..1023
            int d = f & 127;
            int e4 = f >> 7;          // 0..7
            float4 v = *(const float4*)&Wg_l[d * DD + kc * 32 + e4 * 4];
            wg_s[e4 * 4 + 0][d] = v.x;
            wg_s[e4 * 4 + 1][d] = v.y;
            wg_s[e4 * 4 + 2][d] = v.z;
            wg_s[e4 * 4 + 3][d] = v.w;
        }
        __syncthreads();
        #pragma unroll
        for (int kk = 0; kk < 32; ++kk) {
            float hv[4];
            #pragma unroll
            for (int i = 0; i < 4; ++i) hv[i] = h_s[rg * 4 + i][kc * 32 + kk];
            float4 w0 = *(const float4*)&wg_s[kk][dg * 4];
            float4 w1 = *(const float4*)&wg_s[kk][dg * 4 + 64];
            #pragma unroll
            for (int i = 0; i < 4; ++i) {
                acc[i][0] += hv[i] * w0.x; acc[i][1] += hv[i] * w0.y;
                acc[i][2] += hv[i] * w0.z; acc[i][3] += hv[i] * w0.w;
                acc[i][4] += hv[i] * w1.x; acc[i][5] += hv[i] * w1.y;
                acc[i][6] += hv[i] * w1.z; acc[i][7] += hv[i] * w1.w;
            }
        }
    }
    #pragma unroll
    for (int i = 0; i < 4; ++i) {
        int row = row0 + rg * 4 + i;
        float di = dinv[row];
        float4 o0, o1;
        o0.x = acc[i][0] * di; o0.y = acc[i][1] * di; o0.z = acc[i][2] * di; o0.w = acc[i][3] * di;
        o1.x = acc[i][4] * di; o1.y = acc[i][5] * di; o1.z = acc[i][6] * di; o1.w = acc[i][7] * di;
        *(float4*)&t[(size_t)row * DD + dg * 4]      = o0;
        *(float4*)&t[(size_t)row * DD + dg * 4 + 64] = o1;
    }
}

// ---------------------------------------------------------------------------
// K4: aggregation + bias + tanh + residual (in-place h update).
// h_new[b,n,d] = tanh( dinv[n]*( sum_m dist(n,m)*t[b,m,d] + t[b,n,d] ) + bg[d] )
//               + h_old[b,n,d]
// Block tile: 64 n x 128 d, m-chunks of 32; dist regenerated on the fly.
// ---------------------------------------------------------------------------
__global__ __launch_bounds__(256)
void agg_kernel(const float* __restrict__ inst, const float* __restrict__ t,
                const float* __restrict__ dinv, const float* __restrict__ bg_l,
                float* __restrict__ h)
{
    __shared__ float t_s[32][DD];        // 16 KB
    __shared__ float dist_s[64][33];     // 8.4 KB (padded)
    const int b   = blockIdx.x >> 5;     // 32 tiles per batch
    const int n0  = (blockIdx.x & 31) * 64;
    const int tid = threadIdx.x;
    const int dg = tid & 15;             // d = dg*4, dg*4+64
    const int ng = tid >> 4;             // rows n0+ng*4 .. +3
    const int nloc  = tid & 63;          // dist-producer row
    const int mbase = tid >> 6;          // dist-producer m-base

    const float* instb = inst + b * NN * 2;
    const float rx = instb[(n0 + nloc) * 2 + 0];
    const float ry = instb[(n0 + nloc) * 2 + 1];

    float acc[4][8];
    #pragma unroll
    for (int i = 0; i < 4; ++i)
        #pragma unroll
        for (int j = 0; j < 8; ++j) acc[i][j] = 0.f;

    const float* tb = t + (size_t)b * NN * DD;

    for (int k0 = 0; k0 < NN; k0 += 32) {
        __syncthreads();
        // stage t chunk (32x128), coalesced float4
        #pragma unroll
        for (int i = 0; i < 4; ++i) {
            int f = tid + i * 256;       // 0..1023 float4 slots
            int row = f >> 5;
            int c4 = f & 31;
            *(float4*)&t_s[row][c4 * 4] = *(const float4*)&tb[(size_t)(k0 + row) * DD + c4 * 4];
        }
        // dist tile: each thread produces row nloc, m = mbase + 4j (coords via L1, wave-broadcast)
        #pragma unroll
        for (int j = 0; j < 8; ++j) {
            int m = mbase + 4 * j;
            float dx = rx - instb[(k0 + m) * 2 + 0];
            float dy = ry - instb[(k0 + m) * 2 + 1];
            dist_s[nloc][m] = sqrtf(dx * dx + dy * dy);
        }
        __syncthreads();
        #pragma unroll
        for (int m = 0; m < 32; ++m) {
            float dv[4];
            #pragma unroll
            for (int i = 0; i < 4; ++i) dv[i] = dist_s[ng * 4 + i][m];
            float4 t0 = *(const float4*)&t_s[m][dg * 4];
            float4 t1 = *(const float4*)&t_s[m][dg * 4 + 64];
            #pragma unroll
            for (int i = 0; i < 4; ++i) {
                acc[i][0] += dv[i] * t0.x; acc[i][1] += dv[i] * t0.y;
                acc[i][2] += dv[i] * t0.z; acc[i][3] += dv[i] * t0.w;
                acc[i][4] += dv[i] * t1.x; acc[i][5] += dv[i] * t1.y;
                acc[i][6] += dv[i] * t1.z; acc[i][7] += dv[i] * t1.w;
            }
        }
    }
    // epilogue: self-loop term, dinv scale, bias, tanh, residual
    #pragma unroll
    for (int i = 0; i < 4; ++i) {
        int n = n0 + ng * 4 + i;
        float di = dinv[b * NN + n];
        size_t base = ((size_t)b * NN + n) * DD;
        #pragma unroll
        for (int half = 0; half < 2; ++half) {
            int d = dg * 4 + half * 64;
            float4 ts = *(const float4*)&tb[(size_t)n * DD + d];
            float4 ho = *(const float4*)&h[base + d];
            float4 o;
            o.x = tanhf(di * (acc[i][half * 4 + 0] + ts.x) + bg_l[d + 0]) + ho.x;
            o.y = tanhf(di * (acc[i][half * 4 + 1] + ts.y) + bg_l[d + 1]) + ho.y;
            o.z = tanhf(di * (acc[i][half * 4 + 2] + ts.z) + bg_l[d + 2]) + ho.z;
            o.w = tanhf(di * (acc[i][half * 4 + 3] + ts.w) + bg_l[d + 3]) + ho.w;
            *(float4*)&h[base + d] = o;
        }
    }
}

// ---------------------------------------------------------------------------
// K5: GraphNorm partial stats. grid: B*16, each block reduces a 128-row slice.
// ---------------------------------------------------------------------------
__global__ __launch_bounds__(256)
void stats_part_kernel(const float* __restrict__ h, float* __restrict__ psum,
                       float* __restrict__ psq)
{
    __shared__ float red[256];
    const int b     = blockIdx.x >> 4;
    const int slice = blockIdx.x & 15;
    const int tid = threadIdx.x;
    const int d  = tid & 127;
    const int nh = tid >> 7;             // 0/1
    float s = 0.f, q = 0.f;
    #pragma unroll 4
    for (int i = 0; i < 64; ++i) {
        int n = slice * 128 + i * 2 + nh;
        float v = h[((size_t)b * NN + n) * DD + d];
        s += v;
        q += v * v;
    }
    red[tid] = s; __syncthreads();
    if (tid < 128) psum[(b * 16 + slice) * DD + tid] = red[tid] + red[tid + 128];
    __syncthreads();
    red[tid] = q; __syncthreads();
    if (tid < 128) psq[(b * 16 + slice) * DD + tid] = red[tid] + red[tid + 128];
}

// ---------------------------------------------------------------------------
// K6: finalize stats -> am = gn_a*mean, rstd = rsqrt(var+eps)
// var = mean(h^2) - mean^2 * a * (2 - a)
// ---------------------------------------------------------------------------
__global__ __launch_bounds__(256)
void stats_fin_kernel(const float* __restrict__ psum, const float* __restrict__ psq,
                      const float* __restrict__ ga, float* __restrict__ am,
                      float* __restrict__ rstd)
{
    const int idx = blockIdx.x * 256 + threadIdx.x;   // < B*D
    if (idx >= BB * DD) return;
    const int b = idx >> 7;
    const int d = idx & 127;
    float s = 0.f, q = 0.f;
    #pragma unroll
    for (int k = 0; k < 16; ++k) {
        s += psum[(b * 16 + k) * DD + d];
        q += psq[(b * 16 + k) * DD + d];
    }
    const float inv_n = 1.0f / (float)NN;
    float mean = s * inv_n;
    float msq  = q * inv_n;
    float a = ga[d];
    float var = msq - mean * mean * a * (2.0f - a);
    am[idx]   = a * mean;
    rstd[idx] = rsqrtf(var + GN_EPS);
}

// ---------------------------------------------------------------------------
// K7: apply GraphNorm. dst = gn_w * (h - am) * rstd + gn_b
// ---------------------------------------------------------------------------
__global__ __launch_bounds__(256)
void apply_kernel(const float* __restrict__ h, const float* __restrict__ am,
                  const float* __restrict__ rstd, const float* __restrict__ gw,
                  const float* __restrict__ gb, float* __restrict__ dst)
{
    const int idx = blockIdx.x * 256 + threadIdx.x;   // < B*N*D
    const int d = idx & 127;
    const int b = idx >> 18;                          // N*D = 2^18
    float v = (h[idx] - am[b * DD + d]) * rstd[b * DD + d];
    dst[idx] = gw[d] * v + gb[d];
}

// ---------------------------------------------------------------------------
extern "C" void kernel_launch(void* const* d_in, const int* in_sizes, int n_in,
                              void* d_out, int out_size, void* d_ws, size_t ws_size,
                              hipStream_t stream)
{
    const float* inst = (const float*)d_in[0];
    const float* Wn   = (const float*)d_in[1];
    const float* bn   = (const float*)d_in[2];
    const float* Wg   = (const float*)d_in[3];
    const float* bg   = (const float*)d_in[4];
    const float* gw   = (const float*)d_in[5];
    const float* gb   = (const float*)d_in[6];
    const float* ga   = (const float*)d_in[7];
    float* out = (float*)d_out;

    float* ws   = (float*)d_ws;
    float* dinv = ws;                       // B*N            = 16384
    float* h    = dinv + BB * NN;           // B*N*D          = 2097152
    float* t    = h + (size_t)BB * NN * DD; // B*N*D          = 2097152
    float* psum = t + (size_t)BB * NN * DD; // B*16*D         = 16384
    float* psq  = psum + BB * 16 * DD;      // B*16*D         = 16384
    float* am   = psq + BB * 16 * DD;       // B*D            = 1024
    float* rstd = am + BB * DD;             // B*D            = 1024

    deg_kernel<<<BB * 8, 256, 0, stream>>>(inst, dinv);
    proj_kernel<<<(BB * NN * DD) / 256, 256, 0, stream>>>(inst, Wn, bn, h);

    for (int l = 0; l < LL; ++l) {
        lin_kernel<<<(BB * NN) / 64, 256, 0, stream>>>(h, Wg + (size_t)l * DD * DD, dinv, t);
        agg_kernel<<<BB * (NN / 64), 256, 0, stream>>>(inst, t, dinv, bg + l * DD, h);
        stats_part_kernel<<<BB * 16, 256, 0, stream>>>(h, psum, psq);
        stats_fin_kernel<<<(BB * DD + 255) / 256, 256, 0, stream>>>(psum, psq, ga, am, rstd);
        apply_kernel<<<(BB * NN * DD) / 256, 256, 0, stream>>>(
            h, am, rstd, gw, gb, (l == LL - 1) ? out : h);
    }
}

// Round 2
// 406.344 us; speedup vs baseline: 2.0063x; 2.0063x over previous
//
#include <hip/hip_runtime.h>
#include <hip/hip_bf16.h>
#include <math.h>

#define BB 8
#define NN 2048
#define DD 128
#define LL 3
#define GN_EPS 1e-5f

typedef __attribute__((ext_vector_type(8))) short bf16x8;
typedef __attribute__((ext_vector_type(4))) float f32x4;

#define GLL16(gp, lp) __builtin_amdgcn_global_load_lds( \
    (const __attribute__((address_space(1))) void*)(gp), \
    (__attribute__((address_space(3))) void*)(lp), 16, 0, 0)

// round-half-up f32 -> bf16 bits (cheap, bias ~2^-17: negligible)
__device__ __forceinline__ unsigned short f2bf(float f) {
    union { float f; unsigned u; } v; v.f = f;
    return (unsigned short)((v.u + 0x8000u) >> 16);
}

__device__ __forceinline__ float fast_tanh(float x) {
    float e = __expf(-2.0f * fabsf(x));
    float t = (1.0f - e) * __builtin_amdgcn_rcpf(1.0f + e);
    return copysignf(t, x);
}

// ---------------------------------------------------------------------------
// K1: dinv[b*N+i] = rsqrt( sum_j dist(i,j) + 1 )
// ---------------------------------------------------------------------------
__global__ __launch_bounds__(256)
void deg_kernel(const float* __restrict__ inst, float* __restrict__ dinv)
{
    __shared__ float cs[NN * 2];
    const int b  = blockIdx.x >> 3;
    const int i0 = (blockIdx.x & 7) * 256;
    const int tid = threadIdx.x;
    const float* instb = inst + b * NN * 2;
    for (int k = tid; k < NN * 2; k += 256) cs[k] = instb[k];
    __syncthreads();
    const int i = i0 + tid;
    const float xi = cs[i * 2 + 0];
    const float yi = cs[i * 2 + 1];
    float acc = 0.f;
    #pragma unroll 8
    for (int j = 0; j < NN; ++j) {
        float dx = xi - cs[j * 2 + 0];
        float dy = yi - cs[j * 2 + 1];
        acc += sqrtf(dx * dx + dy * dy);
    }
    dinv[b * NN + i] = rsqrtf(acc + 1.0f);
}

// ---------------------------------------------------------------------------
// K2: proj_node
// ---------------------------------------------------------------------------
__global__ __launch_bounds__(256)
void proj_kernel(const float* __restrict__ inst, const float* __restrict__ Wn,
                 const float* __restrict__ bn, float* __restrict__ h)
{
    const int idx = blockIdx.x * 256 + threadIdx.x;
    const int d   = idx & (DD - 1);
    const int row = idx >> 7;
    const float x0 = inst[row * 2 + 0];
    const float x1 = inst[row * 2 + 1];
    h[idx] = x0 * Wn[d * 2 + 0] + x1 * Wn[d * 2 + 1] + bn[d];
}

// ---------------------------------------------------------------------------
// K3: lin + dinv scale -> bf16 transposed output tT[b][d][m]
// ---------------------------------------------------------------------------
__global__ __launch_bounds__(256)
void lin_kernel(const float* __restrict__ h, const float* __restrict__ Wg_l,
                const float* __restrict__ dinv, unsigned short* __restrict__ tT)
{
    __shared__ float h_s[64][132];
    __shared__ float wg_s[32][132];
    const int tid  = threadIdx.x;
    const int row0 = blockIdx.x * 64;
    const int dg = tid & 15;
    const int rg = tid >> 4;

    float acc[4][8];
    #pragma unroll
    for (int i = 0; i < 4; ++i)
        #pragma unroll
        for (int j = 0; j < 8; ++j) acc[i][j] = 0.f;

    #pragma unroll
    for (int i = 0; i < 8; ++i) {
        int f = tid + i * 256;
        int r = f >> 5;
        int c4 = f & 31;
        *(float4*)&h_s[r][c4 * 4] = *(const float4*)&h[(size_t)(row0 + r) * DD + c4 * 4];
    }

    for (int kc = 0; kc < 4; ++kc) {
        __syncthreads();
        #pragma unroll
        for (int i = 0; i < 4; ++i) {
            int f = tid + i * 256;
            int d = f & 127;
            int e4 = f >> 7;
            float4 v = *(const float4*)&Wg_l[d * DD + kc * 32 + e4 * 4];
            wg_s[e4 * 4 + 0][d] = v.x;
            wg_s[e4 * 4 + 1][d] = v.y;
            wg_s[e4 * 4 + 2][d] = v.z;
            wg_s[e4 * 4 + 3][d] = v.w;
        }
        __syncthreads();
        #pragma unroll
        for (int kk = 0; kk < 32; ++kk) {
            float hv[4];
            #pragma unroll
            for (int i = 0; i < 4; ++i) hv[i] = h_s[rg * 4 + i][kc * 32 + kk];
            float4 w0 = *(const float4*)&wg_s[kk][dg * 4];
            float4 w1 = *(const float4*)&wg_s[kk][dg * 4 + 64];
            #pragma unroll
            for (int i = 0; i < 4; ++i) {
                acc[i][0] += hv[i] * w0.x; acc[i][1] += hv[i] * w0.y;
                acc[i][2] += hv[i] * w0.z; acc[i][3] += hv[i] * w0.w;
                acc[i][4] += hv[i] * w1.x; acc[i][5] += hv[i] * w1.y;
                acc[i][6] += hv[i] * w1.z; acc[i][7] += hv[i] * w1.w;
            }
        }
    }
    // epilogue: scale by dinv[row], write bf16 TRANSPOSED: tT[(b*D+d)*N + n]
    const int b     = row0 >> 11;           // same batch for whole 64-row block
    const int nloc0 = (row0 & (NN - 1)) + rg * 4;
    float di[4];
    #pragma unroll
    for (int i = 0; i < 4; ++i) di[i] = dinv[row0 + rg * 4 + i];
    #pragma unroll
    for (int j = 0; j < 8; ++j) {
        int d = dg * 4 + (j & 3) + (j >> 2) * 64;
        ushort4 pk;
        pk.x = f2bf(acc[0][j] * di[0]);
        pk.y = f2bf(acc[1][j] * di[1]);
        pk.z = f2bf(acc[2][j] * di[2]);
        pk.w = f2bf(acc[3][j] * di[3]);
        *(ushort4*)&tT[((size_t)(b * DD + d)) * NN + nloc0] = pk;
    }
}

// ---------------------------------------------------------------------------
// K4: MFMA aggregation + bias + tanh + residual (in-place h update).
// C[n][d] = sum_m A[n][m] * t[m][d],  A = dist + I (diag=1), t has dinv[m].
// Block: 64n x 128d, 4 waves; wave w owns FULL tile over K-range [w*512,(w+1)*512).
// A-frags generated on the fly in registers; B-frags from per-wave LDS tile
// staged via global_load_lds(16B). Barrier-free K-loop; LDS reduction at end.
// ---------------------------------------------------------------------------
__global__ __launch_bounds__(256)
void agg_mfma(const float* __restrict__ inst, const unsigned short* __restrict__ tT,
              const float* __restrict__ dinv, const float* __restrict__ bg_l,
              float* __restrict__ h)
{
    __shared__ float cs[NN * 2];        // 16 KB coords
    __shared__ char  tbuf[4 * 8192];    // 32 KB: per-wave tT tiles, then reduction slot

    const int b    = blockIdx.x >> 5;
    const int nt0  = (blockIdx.x & 31) * 64;
    const int tid  = threadIdx.x;
    const int w    = tid >> 6;
    const int lane = tid & 63;
    const int lq   = lane >> 4;
    const int ll   = lane & 15;

    const float* instb = inst + b * NN * 2;
    for (int i = tid; i < (NN * 2) / 4; i += 256)
        ((float4*)cs)[i] = ((const float4*)instb)[i];
    __syncthreads();

    float nx[4], ny[4];
    #pragma unroll
    for (int nt = 0; nt < 4; ++nt) {
        int n = nt0 + nt * 16 + ll;
        nx[nt] = cs[n * 2 + 0];
        ny[nt] = cs[n * 2 + 1];
    }

    f32x4 acc[4][8];
    #pragma unroll
    for (int nt = 0; nt < 4; ++nt)
        #pragma unroll
        for (int dt = 0; dt < 8; ++dt) acc[nt][dt] = (f32x4)0.0f;

    const unsigned short* tTb = tT + (size_t)b * DD * NN;
    char* mytile = tbuf + w * 8192;
    // per-lane global base: row d=(lane>>2), col offset (lane&3)*8
    const unsigned short* gbase = tTb + (size_t)(lane >> 2) * NN + (lane & 3) * 8;

    for (int kc = 0; kc < 16; ++kc) {
        const int m0 = w * 512 + kc * 32;
        // stage tT tile [128 d][32 m] bf16: 8 issues x 64 lanes x 16B
        #pragma unroll
        for (int i = 0; i < 8; ++i)
            GLL16(gbase + m0 + (size_t)i * 16 * NN, mytile + i * 1024);

        // m coords (shared across the 4 n-frags): pairs m0+lq*8 .. +7
        float mcx[8], mcy[8];
        #pragma unroll
        for (int j = 0; j < 4; ++j) {
            float4 c = *(const float4*)&cs[(m0 + lq * 8) * 2 + j * 4];
            mcx[j * 2 + 0] = c.x; mcy[j * 2 + 0] = c.y;
            mcx[j * 2 + 1] = c.z; mcy[j * 2 + 1] = c.w;
        }
        // A-frags: lane holds A[n = nt0+nt*16+ll][m = m0+lq*8+j], j=0..7
        bf16x8 af[4];
        const bool diag = (m0 < nt0 + 64) && (m0 + 32 > nt0);
        #pragma unroll
        for (int nt = 0; nt < 4; ++nt) {
            #pragma unroll
            for (int j = 0; j < 8; ++j) {
                float dx = nx[nt] - mcx[j];
                float dy = ny[nt] - mcy[j];
                float dist = sqrtf(dx * dx + dy * dy);
                if (diag) {
                    int n = nt0 + nt * 16 + ll;
                    int m = m0 + lq * 8 + j;
                    if (n == m) dist = 1.0f;   // self-loop on the diagonal
                }
                af[nt][j] = (short)f2bf(dist);
            }
        }
        __builtin_amdgcn_s_waitcnt(0x0F70);       // vmcnt(0): tile landed
        __builtin_amdgcn_sched_barrier(0);        // keep ds_reads below the wait
        // B-frags: lane holds B[k=m0l+lq*8+j][n=d-tile*16+ll] = tT[d][m] b128
        #pragma unroll
        for (int dt = 0; dt < 8; ++dt) {
            bf16x8 bf = *(const bf16x8*)(mytile + (dt * 16 + ll) * 64 + lq * 16);
            #pragma unroll
            for (int nt = 0; nt < 4; ++nt)
                acc[nt][dt] = __builtin_amdgcn_mfma_f32_16x16x32_bf16(af[nt], bf, acc[nt][dt], 0, 0, 0);
        }
        __builtin_amdgcn_sched_barrier(0);        // next GLL can't hoist above MFMAs
    }

    // ---- cross-wave reduction (frag-linear layout in LDS, serial into wave 0)
    __syncthreads();
    float* red = (float*)tbuf;   // 32 frags * 64 lanes * 4 f32 = 32 KB
    for (int src = 1; src <= 3; ++src) {
        if (w == src) {
            #pragma unroll
            for (int f = 0; f < 32; ++f)
                *(f32x4*)&red[(f * 64 + lane) * 4] = acc[f >> 3][f & 7];
        }
        __syncthreads();
        if (w == 0) {
            #pragma unroll
            for (int f = 0; f < 32; ++f) {
                f32x4 v = *(const f32x4*)&red[(f * 64 + lane) * 4];
                acc[f >> 3][f & 7] += v;
            }
        }
        __syncthreads();
    }
    if (w == 0) {
        #pragma unroll
        for (int f = 0; f < 32; ++f)
            *(f32x4*)&red[(f * 64 + lane) * 4] = acc[f >> 3][f & 7];
    }
    __syncthreads();

    // ---- cooperative epilogue: wave w takes n-tile nt=w
    float di[4];
    #pragma unroll
    for (int r = 0; r < 4; ++r)
        di[r] = dinv[b * NN + nt0 + w * 16 + lq * 4 + r];
    #pragma unroll
    for (int dt = 0; dt < 8; ++dt) {
        int f = w * 8 + dt;
        f32x4 v = *(const f32x4*)&red[(f * 64 + lane) * 4];
        int d = dt * 16 + ll;
        float bgv = bg_l[d];
        #pragma unroll
        for (int r = 0; r < 4; ++r) {
            int n = nt0 + w * 16 + lq * 4 + r;
            float pre = di[r] * v[r] + bgv;
            size_t idx = ((size_t)b * NN + n) * DD + d;
            h[idx] = fast_tanh(pre) + h[idx];
        }
    }
}

// ---------------------------------------------------------------------------
// K5: GraphNorm partial stats
// ---------------------------------------------------------------------------
__global__ __launch_bounds__(256)
void stats_part_kernel(const float* __restrict__ h, float* __restrict__ psum,
                       float* __restrict__ psq)
{
    __shared__ float red[256];
    const int b     = blockIdx.x >> 4;
    const int slice = blockIdx.x & 15;
    const int tid = threadIdx.x;
    const int nh = tid >> 7;
    float s = 0.f, q = 0.f;
    #pragma unroll 4
    for (int i = 0; i < 64; ++i) {
        int n = slice * 128 + i * 2 + nh;
        float v = h[((size_t)b * NN + n) * DD + (tid & 127)];
        s += v;
        q += v * v;
    }
    red[tid] = s; __syncthreads();
    if (tid < 128) psum[(b * 16 + slice) * DD + tid] = red[tid] + red[tid + 128];
    __syncthreads();
    red[tid] = q; __syncthreads();
    if (tid < 128) psq[(b * 16 + slice) * DD + tid] = red[tid] + red[tid + 128];
}

// ---------------------------------------------------------------------------
// K6: finalize stats
// ---------------------------------------------------------------------------
__global__ __launch_bounds__(256)
void stats_fin_kernel(const float* __restrict__ psum, const float* __restrict__ psq,
                      const float* __restrict__ ga, float* __restrict__ am,
                      float* __restrict__ rstd)
{
    const int idx = blockIdx.x * 256 + threadIdx.x;
    if (idx >= BB * DD) return;
    const int b = idx >> 7;
    const int d = idx & 127;
    float s = 0.f, q = 0.f;
    #pragma unroll
    for (int k = 0; k < 16; ++k) {
        s += psum[(b * 16 + k) * DD + d];
        q += psq[(b * 16 + k) * DD + d];
    }
    const float inv_n = 1.0f / (float)NN;
    float mean = s * inv_n;
    float msq  = q * inv_n;
    float a = ga[d];
    float var = msq - mean * mean * a * (2.0f - a);
    am[idx]   = a * mean;
    rstd[idx] = rsqrtf(var + GN_EPS);
}

// ---------------------------------------------------------------------------
// K7: apply GraphNorm
// ---------------------------------------------------------------------------
__global__ __launch_bounds__(256)
void apply_kernel(const float* __restrict__ h, const float* __restrict__ am,
                  const float* __restrict__ rstd, const float* __restrict__ gw,
                  const float* __restrict__ gb, float* __restrict__ dst)
{
    const int idx = blockIdx.x * 256 + threadIdx.x;
    const int d = idx & 127;
    const int b = idx >> 18;
    float v = (h[idx] - am[b * DD + d]) * rstd[b * DD + d];
    dst[idx] = gw[d] * v + gb[d];
}

// ---------------------------------------------------------------------------
extern "C" void kernel_launch(void* const* d_in, const int* in_sizes, int n_in,
                              void* d_out, int out_size, void* d_ws, size_t ws_size,
                              hipStream_t stream)
{
    const float* inst = (const float*)d_in[0];
    const float* Wn   = (const float*)d_in[1];
    const float* bn   = (const float*)d_in[2];
    const float* Wg   = (const float*)d_in[3];
    const float* bg   = (const float*)d_in[4];
    const float* gw   = (const float*)d_in[5];
    const float* gb   = (const float*)d_in[6];
    const float* ga   = (const float*)d_in[7];
    float* out = (float*)d_out;

    float* ws   = (float*)d_ws;
    float* dinv = ws;                               // B*N
    float* h    = dinv + BB * NN;                   // B*N*D
    unsigned short* tT = (unsigned short*)(h + (size_t)BB * NN * DD); // B*D*N bf16
    float* psum = (float*)(tT + (size_t)BB * DD * NN);
    float* psq  = psum + BB * 16 * DD;
    float* am   = psq + BB * 16 * DD;
    float* rstd = am + BB * DD;

    deg_kernel<<<BB * 8, 256, 0, stream>>>(inst, dinv);
    proj_kernel<<<(BB * NN * DD) / 256, 256, 0, stream>>>(inst, Wn, bn, h);

    for (int l = 0; l < LL; ++l) {
        lin_kernel<<<(BB * NN) / 64, 256, 0, stream>>>(h, Wg + (size_t)l * DD * DD, dinv, tT);
        agg_mfma<<<BB * (NN / 64), 256, 0, stream>>>(inst, tT, dinv, bg + l * DD, h);
        stats_part_kernel<<<BB * 16, 256, 0, stream>>>(h, psum, psq);
        stats_fin_kernel<<<(BB * DD + 255) / 256, 256, 0, stream>>>(psum, psq, ga, am, rstd);
        apply_kernel<<<(BB * NN * DD) / 256, 256, 0, stream>>>(
            h, am, rstd, gw, gb, (l == LL - 1) ? out : h);
    }
}

// Round 3
// 322.925 us; speedup vs baseline: 2.5246x; 1.2583x over previous
//
#include <hip/hip_runtime.h>
#include <hip/hip_bf16.h>
#include <math.h>

#define BB 8
#define NN 2048
#define DD 128
#define LL 3
#define GN_EPS 1e-5f

typedef __attribute__((ext_vector_type(8))) short bf16x8;
typedef __attribute__((ext_vector_type(4))) float f32x4;
typedef __attribute__((ext_vector_type(8))) unsigned short u16x8;

// round-half-up f32 -> bf16 bits
__device__ __forceinline__ unsigned short f2bf(float f) {
    union { float f; unsigned u; } v; v.f = f;
    return (unsigned short)((v.u + 0x8000u) >> 16);
}

__device__ __forceinline__ float fast_tanh(float x) {
    float e = __expf(-2.0f * fabsf(x));
    float t = (1.0f - e) * __builtin_amdgcn_rcpf(1.0f + e);
    return copysignf(t, x);
}

// ---------------------------------------------------------------------------
// K1: gen_adj — materialize A[b][n][m] = dist(n,m) + I  (bf16, diag=1.0)
// and dinv[b][n] = rsqrt(sum_m A[n][m]).  Replaces deg_kernel.
// grid 256 blocks (b x 32 row-tiles of 64), 4 waves, wave owns 16 rows.
// m-coords preloaded to registers once per lane (32 m's per lane).
// ---------------------------------------------------------------------------
__global__ __launch_bounds__(256)
void gen_adj(const float* __restrict__ inst, unsigned short* __restrict__ A,
             float* __restrict__ dinv)
{
    __shared__ float cs[NN * 2];
    const int b   = blockIdx.x >> 5;
    const int n0  = (blockIdx.x & 31) * 64;
    const int tid = threadIdx.x;
    const int w    = tid >> 6;
    const int lane = tid & 63;

    const float* instb = inst + b * NN * 2;
    for (int i = tid; i < (NN * 2) / 4; i += 256)
        ((float4*)cs)[i] = ((const float4*)instb)[i];
    __syncthreads();

    // preload this lane's m-coords: chunks c: m = c*512 + lane*8 + e
    float mx[4][8], my[4][8];
    #pragma unroll
    for (int c = 0; c < 4; ++c)
        #pragma unroll
        for (int e = 0; e < 8; ++e) {
            int m = c * 512 + lane * 8 + e;
            mx[c][e] = cs[m * 2 + 0];
            my[c][e] = cs[m * 2 + 1];
        }

    for (int r = 0; r < 16; ++r) {
        const int n = n0 + w * 16 + r;
        const float nxv = cs[n * 2 + 0];   // uniform -> LDS broadcast
        const float nyv = cs[n * 2 + 1];
        float rs = 0.f;
        unsigned short* Arow = A + ((size_t)b * NN + n) * NN;
        #pragma unroll
        for (int c = 0; c < 4; ++c) {
            const int mb = c * 512 + lane * 8;
            u16x8 pk;
            #pragma unroll
            for (int e = 0; e < 8; ++e) {
                float dx = nxv - mx[c][e];
                float dy = nyv - my[c][e];
                float dist = sqrtf(dx * dx + dy * dy);
                if (mb + e == n) dist = 1.0f;          // self-loop
                rs += dist;
                pk[e] = f2bf(dist);
            }
            *(u16x8*)(Arow + mb) = pk;                 // 16B coalesced
        }
        // wave-wide sum
        #pragma unroll
        for (int off = 1; off < 64; off <<= 1) rs += __shfl_xor(rs, off);
        if (lane == 0) dinv[b * NN + n] = rsqrtf(rs);  // rowsum already has +1
    }
}

// ---------------------------------------------------------------------------
// K2: proj_node + init s=1, c=0 (identity norm for layer 0)
// ---------------------------------------------------------------------------
__global__ __launch_bounds__(256)
void proj_kernel(const float* __restrict__ inst, const float* __restrict__ Wn,
                 const float* __restrict__ bn, float* __restrict__ h,
                 float* __restrict__ sP, float* __restrict__ cP)
{
    const int idx = blockIdx.x * 256 + threadIdx.x;
    const int d   = idx & (DD - 1);
    const int row = idx >> 7;
    const float x0 = inst[row * 2 + 0];
    const float x1 = inst[row * 2 + 1];
    h[idx] = x0 * Wn[d * 2 + 0] + x1 * Wn[d * 2 + 1] + bn[d];
    if (blockIdx.x == 0) {
        for (int i = threadIdx.x; i < BB * DD; i += 256) { sP[i] = 1.0f; cP[i] = 0.0f; }
    }
}

// ---------------------------------------------------------------------------
// K3: lin (MFMA) — tT[b][d'][m] = bf16( dinv[m] * sum_e (s*h+c)[m][e] * Wg[d'][e] )
// Block: 32 nodes x all 128 d'.  grid 256.  Wave w owns d' in [w*32, w*32+32).
// Also zeroes psum/psq (block 0) for this layer's fused stats.
// ---------------------------------------------------------------------------
__global__ __launch_bounds__(256)
void lin_mfma(const float* __restrict__ h, const float* __restrict__ Wg_l,
              const float* __restrict__ dinv, const float* __restrict__ sP,
              const float* __restrict__ cP, unsigned short* __restrict__ tT,
              float* __restrict__ psum, float* __restrict__ psq)
{
    __shared__ unsigned short wg_s[DD][136];   // +8 pad: 2-way banks only
    __shared__ unsigned short h_s[32][136];
    const int tid  = threadIdx.x;
    const int row0 = blockIdx.x * 32;          // global node row
    const int b    = row0 >> 11;
    const int w    = tid >> 6;
    const int lane = tid & 63;
    const int lq   = lane >> 4;
    const int ll   = lane & 15;

    if (blockIdx.x == 0) {
        for (int i = tid; i < BB * DD; i += 256) { psum[i] = 0.f; psq[i] = 0.f; }
    }

    // stage Wg (128x128) -> bf16
    #pragma unroll
    for (int i = 0; i < 16; ++i) {
        int f = tid + i * 256;                 // 0..4095 float4 slots
        int rr = f >> 5, c4 = f & 31;
        float4 v = *(const float4*)&Wg_l[rr * DD + c4 * 4];
        ushort4 p = { f2bf(v.x), f2bf(v.y), f2bf(v.z), f2bf(v.w) };
        *(ushort4*)&wg_s[rr][c4 * 4] = p;
    }
    // stage h_norm tile (32x128) -> bf16
    #pragma unroll
    for (int i = 0; i < 4; ++i) {
        int f = tid + i * 256;                 // 0..1023
        int rr = f >> 5, c4 = f & 31;
        float4 hv = *(const float4*)&h[(size_t)(row0 + rr) * DD + c4 * 4];
        float4 sv = *(const float4*)&sP[b * DD + c4 * 4];
        float4 cv = *(const float4*)&cP[b * DD + c4 * 4];
        ushort4 p = { f2bf(fmaf(sv.x, hv.x, cv.x)), f2bf(fmaf(sv.y, hv.y, cv.y)),
                      f2bf(fmaf(sv.z, hv.z, cv.z)), f2bf(fmaf(sv.w, hv.w, cv.w)) };
        *(ushort4*)&h_s[rr][c4 * 4] = p;
    }
    __syncthreads();

    f32x4 acc[2][2];                           // [mt][ntile]
    #pragma unroll
    for (int i = 0; i < 2; ++i)
        #pragma unroll
        for (int j = 0; j < 2; ++j) acc[i][j] = (f32x4)0.0f;

    #pragma unroll
    for (int kc = 0; kc < 4; ++kc) {
        bf16x8 a0 = *(const bf16x8*)&wg_s[(2 * w + 0) * 16 + ll][kc * 32 + lq * 8];
        bf16x8 a1 = *(const bf16x8*)&wg_s[(2 * w + 1) * 16 + ll][kc * 32 + lq * 8];
        bf16x8 b0 = *(const bf16x8*)&h_s[0 * 16 + ll][kc * 32 + lq * 8];
        bf16x8 b1 = *(const bf16x8*)&h_s[1 * 16 + ll][kc * 32 + lq * 8];
        acc[0][0] = __builtin_amdgcn_mfma_f32_16x16x32_bf16(a0, b0, acc[0][0], 0, 0, 0);
        acc[0][1] = __builtin_amdgcn_mfma_f32_16x16x32_bf16(a0, b1, acc[0][1], 0, 0, 0);
        acc[1][0] = __builtin_amdgcn_mfma_f32_16x16x32_bf16(a1, b0, acc[1][0], 0, 0, 0);
        acc[1][1] = __builtin_amdgcn_mfma_f32_16x16x32_bf16(a1, b1, acc[1][1], 0, 0, 0);
    }

    // store tT (C row = d', col = node), fold dinv[node]
    const int nbase = row0 & (NN - 1);
    #pragma unroll
    for (int nt = 0; nt < 2; ++nt) {
        const int nloc = nbase + nt * 16 + ll;
        const float di = dinv[row0 + nt * 16 + ll];
        #pragma unroll
        for (int mt = 0; mt < 2; ++mt) {
            #pragma unroll
            for (int reg = 0; reg < 4; ++reg) {
                int dp = (2 * w + mt) * 16 + lq * 4 + reg;
                tT[((size_t)(b * DD + dp)) * NN + nloc] = f2bf(acc[mt][nt][reg] * di);
            }
        }
    }
}

// ---------------------------------------------------------------------------
// K4: agg (MFMA, no LDS, no barriers) + bias + tanh + residual(s*h+c) + stats.
// C[n][d] = sum_m A[n][m] * t[m][d].  Block: 32n x 128d, grid 512 (2/CU).
// Wave w owns d-tiles {2w, 2w+1}, full K=2048.  Double-buffered 128-m chunks
// of register frags loaded directly from global (compiler pipelines vmcnt).
// ---------------------------------------------------------------------------
__global__ __launch_bounds__(256)
void agg_mfma(const unsigned short* __restrict__ A, const unsigned short* __restrict__ tT,
              const float* __restrict__ dinv, const float* __restrict__ bg_l,
              const float* __restrict__ sP, const float* __restrict__ cP,
              float* __restrict__ h, float* __restrict__ psum, float* __restrict__ psq)
{
    const int b   = blockIdx.x >> 6;
    const int n0  = (blockIdx.x & 63) * 32;
    const int tid = threadIdx.x;
    const int w    = tid >> 6;
    const int lane = tid & 63;
    const int lq   = lane >> 4;
    const int ll   = lane & 15;

    const unsigned short* Ab  = A  + ((size_t)b * NN + n0) * NN;
    const unsigned short* tTb = tT + (size_t)b * DD * NN;

    const unsigned short* ap[2];
    const unsigned short* bp[2];
    ap[0] = Ab + (0 * 16 + ll) * NN + lq * 8;
    ap[1] = Ab + (1 * 16 + ll) * NN + lq * 8;
    bp[0] = tTb + (size_t)((2 * w + 0) * 16 + ll) * NN + lq * 8;
    bp[1] = tTb + (size_t)((2 * w + 1) * 16 + ll) * NN + lq * 8;

    f32x4 acc[2][2];                   // [nt][dt]
    #pragma unroll
    for (int i = 0; i < 2; ++i)
        #pragma unroll
        for (int j = 0; j < 2; ++j) acc[i][j] = (f32x4)0.0f;

    bf16x8 fa[2][4][2], fb[2][4][2];   // [buf][stage][nt/dt]

#define LOADCHUNK(buf, m0)                                                     \
    {                                                                          \
        _Pragma("unroll")                                                      \
        for (int s = 0; s < 4; ++s) {                                          \
            int mm = (m0) + s * 32;                                            \
            fa[buf][s][0] = *(const bf16x8*)(ap[0] + mm);                      \
            fa[buf][s][1] = *(const bf16x8*)(ap[1] + mm);                      \
            fb[buf][s][0] = *(const bf16x8*)(bp[0] + mm);                      \
            fb[buf][s][1] = *(const bf16x8*)(bp[1] + mm);                      \
        }                                                                      \
    }
#define DOMFMA(buf)                                                            \
    {                                                                          \
        _Pragma("unroll")                                                      \
        for (int s = 0; s < 4; ++s) {                                          \
            _Pragma("unroll")                                                  \
            for (int nt = 0; nt < 2; ++nt)                                     \
                _Pragma("unroll")                                              \
                for (int dt = 0; dt < 2; ++dt)                                 \
                    acc[nt][dt] = __builtin_amdgcn_mfma_f32_16x16x32_bf16(     \
                        fa[buf][s][nt], fb[buf][s][dt], acc[nt][dt], 0, 0, 0); \
        }                                                                      \
    }

    LOADCHUNK(0, 0)
    for (int m0 = 0; m0 < NN; m0 += 256) {
        LOADCHUNK(1, (m0 + 128) & (NN - 1))
        DOMFMA(0)
        LOADCHUNK(0, (m0 + 256) & (NN - 1))
        DOMFMA(1)
    }
#undef LOADCHUNK
#undef DOMFMA

    // epilogue: dinv[n]*acc + bg -> tanh -> + (s*h+c); fused stats atomics
    float dv[2][4];
    #pragma unroll
    for (int nt = 0; nt < 2; ++nt)
        #pragma unroll
        for (int reg = 0; reg < 4; ++reg)
            dv[nt][reg] = dinv[b * NN + n0 + nt * 16 + lq * 4 + reg];

    #pragma unroll
    for (int dtl = 0; dtl < 2; ++dtl) {
        const int d = (2 * w + dtl) * 16 + ll;
        const float bg = bg_l[d];
        const float sv = sP[b * DD + d];
        const float cv = cP[b * DD + d];
        float hs = 0.f, hq = 0.f;
        #pragma unroll
        for (int nt = 0; nt < 2; ++nt) {
            #pragma unroll
            for (int reg = 0; reg < 4; ++reg) {
                int n = n0 + nt * 16 + lq * 4 + reg;
                size_t idx = ((size_t)b * NN + n) * DD + d;
                float pre = dv[nt][reg] * acc[nt][dtl][reg] + bg;
                float out = fast_tanh(pre) + fmaf(sv, h[idx], cv);
                h[idx] = out;
                hs += out;
                hq += out * out;
            }
        }
        hs += __shfl_xor(hs, 16); hs += __shfl_xor(hs, 32);
        hq += __shfl_xor(hq, 16); hq += __shfl_xor(hq, 32);
        if (lq == 0) {
            atomicAdd(&psum[b * DD + d], hs);
            atomicAdd(&psq[b * DD + d], hq);
        }
    }
}

// ---------------------------------------------------------------------------
// K5: finalize stats -> s = gw*rstd, c = gb - s*(a*mean)
// ---------------------------------------------------------------------------
__global__ __launch_bounds__(256)
void stats_fin_kernel(const float* __restrict__ psum, const float* __restrict__ psq,
                      const float* __restrict__ ga, const float* __restrict__ gw,
                      const float* __restrict__ gb, float* __restrict__ sP,
                      float* __restrict__ cP)
{
    const int idx = blockIdx.x * 256 + threadIdx.x;
    if (idx >= BB * DD) return;
    const int d = idx & 127;
    const float inv_n = 1.0f / (float)NN;
    float mean = psum[idx] * inv_n;
    float msq  = psq[idx] * inv_n;
    float a = ga[d];
    float var = msq - mean * mean * a * (2.0f - a);
    float rstd = rsqrtf(var + GN_EPS);
    float s = gw[d] * rstd;
    sP[idx] = s;
    cP[idx] = gb[d] - s * (a * mean);
}

// ---------------------------------------------------------------------------
// K6: final apply: out = s*h + c
// ---------------------------------------------------------------------------
__global__ __launch_bounds__(256)
void apply_kernel(const float* __restrict__ h, const float* __restrict__ sP,
                  const float* __restrict__ cP, float* __restrict__ dst)
{
    const int idx = blockIdx.x * 256 + threadIdx.x;
    const int d = idx & 127;
    const int b = idx >> 18;
    dst[idx] = fmaf(sP[b * DD + d], h[idx], cP[b * DD + d]);
}

// ---------------------------------------------------------------------------
extern "C" void kernel_launch(void* const* d_in, const int* in_sizes, int n_in,
                              void* d_out, int out_size, void* d_ws, size_t ws_size,
                              hipStream_t stream)
{
    const float* inst = (const float*)d_in[0];
    const float* Wn   = (const float*)d_in[1];
    const float* bn   = (const float*)d_in[2];
    const float* Wg   = (const float*)d_in[3];
    const float* bg   = (const float*)d_in[4];
    const float* gw   = (const float*)d_in[5];
    const float* gb   = (const float*)d_in[6];
    const float* ga   = (const float*)d_in[7];
    float* out = (float*)d_out;

    float* ws   = (float*)d_ws;
    float* dinv = ws;                                   // 16384
    float* h    = dinv + BB * NN;                       // 2097152
    float* psum = h + (size_t)BB * NN * DD;             // 1024
    float* psq  = psum + BB * DD;                       // 1024
    float* sP   = psq + BB * DD;                        // 1024
    float* cP   = sP + BB * DD;                         // 1024
    unsigned short* tT = (unsigned short*)(cP + BB * DD);        // B*D*N bf16
    unsigned short* A  = tT + (size_t)BB * DD * NN;              // B*N*N bf16 (64MB)

    gen_adj<<<BB * 32, 256, 0, stream>>>(inst, A, dinv);
    proj_kernel<<<(BB * NN * DD) / 256, 256, 0, stream>>>(inst, Wn, bn, h, sP, cP);

    for (int l = 0; l < LL; ++l) {
        lin_mfma<<<(BB * NN) / 32, 256, 0, stream>>>(
            h, Wg + (size_t)l * DD * DD, dinv, sP, cP, tT, psum, psq);
        agg_mfma<<<BB * (NN / 32), 256, 0, stream>>>(
            A, tT, dinv, bg + l * DD, sP, cP, h, psum, psq);
        stats_fin_kernel<<<(BB * DD + 255) / 256, 256, 0, stream>>>(
            psum, psq, ga, gw, gb, sP, cP);
    }
    apply_kernel<<<(BB * NN * DD) / 256, 256, 0, stream>>>(h, sP, cP, out);
}

// Round 4
// 263.791 us; speedup vs baseline: 3.0906x; 1.2242x over previous
//
#include <hip/hip_runtime.h>
#include <hip/hip_bf16.h>
#include <math.h>

#define BB 8
#define NN 2048
#define DD 128
#define LL 3
#define GN_EPS 1e-5f

typedef __attribute__((ext_vector_type(8))) short bf16x8;
typedef __attribute__((ext_vector_type(4))) float f32x4;
typedef __attribute__((ext_vector_type(8))) unsigned short u16x8;

#define GLL16(gp, lp) __builtin_amdgcn_global_load_lds( \
    (const __attribute__((address_space(1))) void*)(gp), \
    (__attribute__((address_space(3))) void*)(lp), 16, 0, 0)

// s_waitcnt imm: vmcnt low4 bits[3:0], high2 bits[15:14]; exp=7 bits[6:4]; lgkm=15 bits[11:8]
#define WAITCNT_VM18 0x4F72   // vmcnt(18), no lgkm/exp wait
 
// round-half-up f32 -> bf16 bits
__device__ __forceinline__ unsigned short f2bf(float f) {
    union { float f; unsigned u; } v; v.f = f;
    return (unsigned short)((v.u + 0x8000u) >> 16);
}

__device__ __forceinline__ float fast_tanh(float x) {
    float e = __expf(-2.0f * fabsf(x));
    float t = (1.0f - e) * __builtin_amdgcn_rcpf(1.0f + e);
    return copysignf(t, x);
}

// ---------------------------------------------------------------------------
// K0: prep_wg — pack Wg (3x128x128 f32) into bf16 MFMA A-frag order:
// wgf[(((l*8+dpt)*4+kc)*16+ll)*32 + lq*8 + e] = bf16(Wg[l][dpt*16+ll][kc*32+lq*8+e])
// ---------------------------------------------------------------------------
__global__ __launch_bounds__(256)
void prep_wg(const float* __restrict__ Wg, unsigned short* __restrict__ wgf)
{
    const int f = blockIdx.x * 256 + threadIdx.x;    // < 3*128*128
    const int l  = f >> 14;
    const int r  = f & 16383;
    const int dp = r >> 7;
    const int e  = r & 127;
    const int dpt = dp >> 4, ll = dp & 15;
    const int kc  = e >> 5,  eo = e & 31;
    wgf[((((l * 8 + dpt) * 4 + kc) * 16 + ll) << 5) + eo] = f2bf(Wg[f]);
}

// ---------------------------------------------------------------------------
// K1: gen_adj — A[b][n][m] = dist(n,m) + I (bf16), dinv = rsqrt(rowsum).
// grid 512 (b x 64 tiles of 32 rows), 4 waves, wave owns 8 rows.
// ---------------------------------------------------------------------------
__global__ __launch_bounds__(256)
void gen_adj(const float* __restrict__ inst, unsigned short* __restrict__ A,
             float* __restrict__ dinv)
{
    __shared__ float cs[NN * 2];
    const int b   = blockIdx.x >> 6;
    const int n0  = (blockIdx.x & 63) * 32;
    const int tid = threadIdx.x;
    const int w    = tid >> 6;
    const int lane = tid & 63;

    const float* instb = inst + b * NN * 2;
    for (int i = tid; i < (NN * 2) / 4; i += 256)
        ((float4*)cs)[i] = ((const float4*)instb)[i];
    __syncthreads();

    float mx[4][8], my[4][8];
    #pragma unroll
    for (int c = 0; c < 4; ++c)
        #pragma unroll
        for (int e = 0; e < 8; ++e) {
            int m = c * 512 + lane * 8 + e;
            mx[c][e] = cs[m * 2 + 0];
            my[c][e] = cs[m * 2 + 1];
        }

    for (int r = 0; r < 8; ++r) {
        const int n = n0 + w * 8 + r;
        const float nxv = cs[n * 2 + 0];
        const float nyv = cs[n * 2 + 1];
        float rs = 0.f;
        unsigned short* Arow = A + ((size_t)b * NN + n) * NN;
        #pragma unroll
        for (int c = 0; c < 4; ++c) {
            const int mb = c * 512 + lane * 8;
            u16x8 pk;
            #pragma unroll
            for (int e = 0; e < 8; ++e) {
                float dx = nxv - mx[c][e];
                float dy = nyv - my[c][e];
                float dist = sqrtf(dx * dx + dy * dy);
                if (mb + e == n) dist = 1.0f;          // self-loop
                rs += dist;
                pk[e] = f2bf(dist);
            }
            *(u16x8*)(Arow + mb) = pk;
        }
        #pragma unroll
        for (int off = 1; off < 64; off <<= 1) rs += __shfl_xor(rs, off);
        if (lane == 0) dinv[b * NN + n] = rsqrtf(rs);
    }
}

// ---------------------------------------------------------------------------
// K2: proj_node + init sP=1, cP=0, psum=psq=0
// ---------------------------------------------------------------------------
__global__ __launch_bounds__(256)
void proj_kernel(const float* __restrict__ inst, const float* __restrict__ Wn,
                 const float* __restrict__ bn, float* __restrict__ h,
                 float* __restrict__ sP, float* __restrict__ cP,
                 float* __restrict__ psum, float* __restrict__ psq)
{
    const int idx = blockIdx.x * 256 + threadIdx.x;
    const int d   = idx & (DD - 1);
    const int row = idx >> 7;
    const float x0 = inst[row * 2 + 0];
    const float x1 = inst[row * 2 + 1];
    h[idx] = x0 * Wn[d * 2 + 0] + x1 * Wn[d * 2 + 1] + bn[d];
    if (blockIdx.x == 0) {
        for (int i = threadIdx.x; i < BB * DD; i += 256) {
            sP[i] = 1.0f; cP[i] = 0.0f; psum[i] = 0.0f; psq[i] = 0.0f;
        }
    }
}

// ---------------------------------------------------------------------------
// K3: lin (MFMA, no LDS, no barriers).
// tT[b][d'][m] = bf16( dinv[m] * sum_e (s*h+c)[m][e] * Wg[d'][e] )
// Block 32 nodes, grid 512. Wave w: d'-tiles {2w,2w+1}; Wg frags preloaded
// from wgf (contiguous per-lane 16B). h-frags built in registers.
// ---------------------------------------------------------------------------
__global__ __launch_bounds__(256)
void lin_mfma(const float* __restrict__ h, const unsigned short* __restrict__ wgf_l,
              const float* __restrict__ dinv, const float* __restrict__ sP,
              const float* __restrict__ cP, unsigned short* __restrict__ tT)
{
    const int tid  = threadIdx.x;
    const int row0 = blockIdx.x * 32;
    const int b    = row0 >> 11;
    const int w    = tid >> 6;
    const int lane = tid & 63;
    const int lq   = lane >> 4;
    const int ll   = lane & 15;

    // Wg A-frags: [mt][kc], addr = (((dpt*4+kc)*16+ll)*32 + lq*8)
    bf16x8 aw[2][4];
    #pragma unroll
    for (int mt = 0; mt < 2; ++mt) {
        const int dpt = 2 * w + mt;
        #pragma unroll
        for (int kc = 0; kc < 4; ++kc)
            aw[mt][kc] = *(const bf16x8*)&wgf_l[(((dpt * 4 + kc) * 16 + ll) << 5) + lq * 8];
    }

    // norm scale/shift for this lane's e-slice (per kc): e = kc*32 + lq*8 ..+7
    float sv[4][8], cv[4][8];
    #pragma unroll
    for (int kc = 0; kc < 4; ++kc) {
        #pragma unroll
        for (int half = 0; half < 2; ++half) {
            float4 s4 = *(const float4*)&sP[b * DD + kc * 32 + lq * 8 + half * 4];
            float4 c4 = *(const float4*)&cP[b * DD + kc * 32 + lq * 8 + half * 4];
            sv[kc][half * 4 + 0] = s4.x; sv[kc][half * 4 + 1] = s4.y;
            sv[kc][half * 4 + 2] = s4.z; sv[kc][half * 4 + 3] = s4.w;
            cv[kc][half * 4 + 0] = c4.x; cv[kc][half * 4 + 1] = c4.y;
            cv[kc][half * 4 + 2] = c4.z; cv[kc][half * 4 + 3] = c4.w;
        }
    }

    // h B-frags: [nt][kc]: lane = node nt*16+ll, e = kc*32+lq*8..+7
    bf16x8 bh[2][4];
    #pragma unroll
    for (int nt = 0; nt < 2; ++nt) {
        const float* hrow = h + (size_t)(row0 + nt * 16 + ll) * DD;
        #pragma unroll
        for (int kc = 0; kc < 4; ++kc) {
            float4 h0 = *(const float4*)&hrow[kc * 32 + lq * 8];
            float4 h1 = *(const float4*)&hrow[kc * 32 + lq * 8 + 4];
            bf16x8 p;
            p[0] = (short)f2bf(fmaf(sv[kc][0], h0.x, cv[kc][0]));
            p[1] = (short)f2bf(fmaf(sv[kc][1], h0.y, cv[kc][1]));
            p[2] = (short)f2bf(fmaf(sv[kc][2], h0.z, cv[kc][2]));
            p[3] = (short)f2bf(fmaf(sv[kc][3], h0.w, cv[kc][3]));
            p[4] = (short)f2bf(fmaf(sv[kc][4], h1.x, cv[kc][4]));
            p[5] = (short)f2bf(fmaf(sv[kc][5], h1.y, cv[kc][5]));
            p[6] = (short)f2bf(fmaf(sv[kc][6], h1.z, cv[kc][6]));
            p[7] = (short)f2bf(fmaf(sv[kc][7], h1.w, cv[kc][7]));
            bh[nt][kc] = p;
        }
    }

    f32x4 acc[2][2];   // [mt][nt]
    #pragma unroll
    for (int i = 0; i < 2; ++i)
        #pragma unroll
        for (int j = 0; j < 2; ++j) acc[i][j] = (f32x4)0.0f;

    #pragma unroll
    for (int kc = 0; kc < 4; ++kc)
        #pragma unroll
        for (int mt = 0; mt < 2; ++mt)
            #pragma unroll
            for (int nt = 0; nt < 2; ++nt)
                acc[mt][nt] = __builtin_amdgcn_mfma_f32_16x16x32_bf16(
                    aw[mt][kc], bh[nt][kc], acc[mt][nt], 0, 0, 0);

    // store tT transposed with dinv folded
    const int nbase = row0 & (NN - 1);
    #pragma unroll
    for (int nt = 0; nt < 2; ++nt) {
        const int nloc = nbase + nt * 16 + ll;
        const float di = dinv[row0 + nt * 16 + ll];
        #pragma unroll
        for (int mt = 0; mt < 2; ++mt) {
            #pragma unroll
            for (int reg = 0; reg < 4; ++reg) {
                int dp = (2 * w + mt) * 16 + lq * 4 + reg;
                tT[((size_t)(b * DD + dp)) * NN + nloc] = f2bf(acc[mt][nt][reg] * di);
            }
        }
    }
}

// ---------------------------------------------------------------------------
// K4: agg — LDS-pipelined MFMA GEMM + bias + tanh + residual + fused stats.
// C[n][d] = sum_m A[n][m]*t[m][d].  Block 32n x 128d, grid 512, 4 waves.
// K-chunks of 128 m; A staged frag-linear into 3 LDS buffers via
// global_load_lds (each wave stages 2 of 8 frags), prefetch distance 2,
// explicit vmcnt(18) + raw s_barrier (no drain). tT in 2-deep reg buffer.
// ---------------------------------------------------------------------------
__global__ __launch_bounds__(256)
void agg_mfma(const unsigned short* __restrict__ A, const unsigned short* __restrict__ tT,
              const float* __restrict__ dinv, const float* __restrict__ bg_l,
              const float* __restrict__ sP, const float* __restrict__ cP,
              float* __restrict__ h, float* __restrict__ psum, float* __restrict__ psq)
{
    __shared__ unsigned short Abuf[3][8 * 512];   // 3 x 8KB, frag-linear
    const int b   = blockIdx.x >> 6;
    const int n0  = (blockIdx.x & 63) * 32;
    const int tid = threadIdx.x;
    const int w    = tid >> 6;
    const int lane = tid & 63;
    const int lq   = lane >> 4;
    const int ll   = lane & 15;

    const unsigned short* Ab  = A  + ((size_t)b * NN + n0) * NN;
    const unsigned short* tTb = tT + (size_t)b * DD * NN;

    // wave stages frags f0=2w, f1=2w+1; frag f = nt*4+s -> [16n][32m] gather
    const int f0 = 2 * w, f1 = 2 * w + 1;
    const unsigned short* ga0 = Ab + (size_t)((f0 >> 2) * 16 + ll) * NN + (f0 & 3) * 32 + lq * 8;
    const unsigned short* ga1 = Ab + (size_t)((f1 >> 2) * 16 + ll) * NN + (f1 & 3) * 32 + lq * 8;

    // B rows (tT d-rows) owned by this wave
    const unsigned short* gb0 = tTb + (size_t)((2 * w + 0) * 16 + ll) * NN + lq * 8;
    const unsigned short* gb1 = tTb + (size_t)((2 * w + 1) * 16 + ll) * NN + lq * 8;

    f32x4 acc[2][2];        // [nt][dt]
    #pragma unroll
    for (int i = 0; i < 2; ++i)
        #pragma unroll
        for (int j = 0; j < 2; ++j) acc[i][j] = (f32x4)0.0f;

    bf16x8 fB[2][2][4];     // [buf][dt][s]

#define GLLA(c) { \
        const int m0_ = ((c) & 15) * 128; \
        unsigned short* lb_ = &Abuf[(c) % 3][0]; \
        GLL16(ga0 + m0_, lb_ + f0 * 512); \
        GLL16(ga1 + m0_, lb_ + f1 * 512); \
    }
#define LOADB(c) { \
        const int m0_ = ((c) & 15) * 128; \
        _Pragma("unroll") \
        for (int s_ = 0; s_ < 4; ++s_) { \
            fB[(c) & 1][0][s_] = *(const bf16x8*)(gb0 + m0_ + s_ * 32); \
            fB[(c) & 1][1][s_] = *(const bf16x8*)(gb1 + m0_ + s_ * 32); \
        } \
    }

    // prologue: A(0), A(1), B(0)  -> per-wave vm order: 2,2,8
    GLLA(0)
    GLLA(1)
    LOADB(0)

    #pragma unroll
    for (int k = 0; k < 16; ++k) {
        __builtin_amdgcn_s_waitcnt(WAITCNT_VM18);   // A(k) landed (wave-local)
        __builtin_amdgcn_s_barrier();               // all waves' A(k) landed
        __builtin_amdgcn_sched_barrier(0);

        // read all 8 A-frags (conflict-free: addr = lane*16 within each 1KB frag)
        bf16x8 af[2][4];
        const unsigned short* lb = &Abuf[k % 3][0];
        #pragma unroll
        for (int nt = 0; nt < 2; ++nt)
            #pragma unroll
            for (int s = 0; s < 4; ++s)
                af[nt][s] = *(const bf16x8*)(lb + (nt * 4 + s) * 512 + lane * 8);

        // prefetch next: A(k+2) -> LDS, B(k+1) -> regs (wrap-safe)
        GLLA(k + 2)
        LOADB(k + 1)

        #pragma unroll
        for (int s = 0; s < 4; ++s)
            #pragma unroll
            for (int nt = 0; nt < 2; ++nt)
                #pragma unroll
                for (int dt = 0; dt < 2; ++dt)
                    acc[nt][dt] = __builtin_amdgcn_mfma_f32_16x16x32_bf16(
                        af[nt][s], fB[k & 1][dt][s], acc[nt][dt], 0, 0, 0);
    }
#undef GLLA
#undef LOADB

    // epilogue: dinv[n]*acc + bg -> tanh -> + (s*h+c); fused stats atomics
    float dv[2][4];
    #pragma unroll
    for (int nt = 0; nt < 2; ++nt)
        #pragma unroll
        for (int reg = 0; reg < 4; ++reg)
            dv[nt][reg] = dinv[b * NN + n0 + nt * 16 + lq * 4 + reg];

    #pragma unroll
    for (int dtl = 0; dtl < 2; ++dtl) {
        const int d = (2 * w + dtl) * 16 + ll;
        const float bg = bg_l[d];
        const float sv = sP[b * DD + d];
        const float cv = cP[b * DD + d];
        float hs = 0.f, hq = 0.f;
        #pragma unroll
        for (int nt = 0; nt < 2; ++nt) {
            #pragma unroll
            for (int reg = 0; reg < 4; ++reg) {
                int n = n0 + nt * 16 + lq * 4 + reg;
                size_t idx = ((size_t)b * NN + n) * DD + d;
                float pre = dv[nt][reg] * acc[nt][dtl][reg] + bg;
                float out = fast_tanh(pre) + fmaf(sv, h[idx], cv);
                h[idx] = out;
                hs += out;
                hq += out * out;
            }
        }
        hs += __shfl_xor(hs, 16); hs += __shfl_xor(hs, 32);
        hq += __shfl_xor(hq, 16); hq += __shfl_xor(hq, 32);
        if (lq == 0) {
            atomicAdd(&psum[b * DD + d], hs);
            atomicAdd(&psq[b * DD + d], hq);
        }
    }
}

// ---------------------------------------------------------------------------
// K5: finalize stats -> s = gw*rstd, c = gb - s*(a*mean); re-zero psum/psq
// ---------------------------------------------------------------------------
__global__ __launch_bounds__(256)
void stats_fin_kernel(float* __restrict__ psum, float* __restrict__ psq,
                      const float* __restrict__ ga, const float* __restrict__ gw,
                      const float* __restrict__ gb, float* __restrict__ sP,
                      float* __restrict__ cP)
{
    const int idx = blockIdx.x * 256 + threadIdx.x;
    if (idx >= BB * DD) return;
    const int d = idx & 127;
    const float inv_n = 1.0f / (float)NN;
    float mean = psum[idx] * inv_n;
    float msq  = psq[idx] * inv_n;
    float a = ga[d];
    float var = msq - mean * mean * a * (2.0f - a);
    float rstd = rsqrtf(var + GN_EPS);
    float s = gw[d] * rstd;
    sP[idx] = s;
    cP[idx] = gb[d] - s * (a * mean);
    psum[idx] = 0.0f;
    psq[idx]  = 0.0f;
}

// ---------------------------------------------------------------------------
// K6: final apply: out = s*h + c  (float4)
// ---------------------------------------------------------------------------
__global__ __launch_bounds__(256)
void apply_kernel(const float* __restrict__ h, const float* __restrict__ sP,
                  const float* __restrict__ cP, float* __restrict__ dst)
{
    const int i4 = blockIdx.x * 256 + threadIdx.x;    // < B*N*D/4
    const int dg = (i4 & 31) * 4;
    const int b  = i4 >> 16;                          // N*D/4 = 65536
    float4 hv = ((const float4*)h)[i4];
    float4 s4 = *(const float4*)&sP[b * DD + dg];
    float4 c4 = *(const float4*)&cP[b * DD + dg];
    float4 o;
    o.x = fmaf(s4.x, hv.x, c4.x);
    o.y = fmaf(s4.y, hv.y, c4.y);
    o.z = fmaf(s4.z, hv.z, c4.z);
    o.w = fmaf(s4.w, hv.w, c4.w);
    ((float4*)dst)[i4] = o;
}

// ---------------------------------------------------------------------------
extern "C" void kernel_launch(void* const* d_in, const int* in_sizes, int n_in,
                              void* d_out, int out_size, void* d_ws, size_t ws_size,
                              hipStream_t stream)
{
    const float* inst = (const float*)d_in[0];
    const float* Wn   = (const float*)d_in[1];
    const float* bn   = (const float*)d_in[2];
    const float* Wg   = (const float*)d_in[3];
    const float* bg   = (const float*)d_in[4];
    const float* gw   = (const float*)d_in[5];
    const float* gb   = (const float*)d_in[6];
    const float* ga   = (const float*)d_in[7];
    float* out = (float*)d_out;

    float* ws   = (float*)d_ws;
    float* dinv = ws;                                   // 16384
    float* h    = dinv + BB * NN;                       // 2097152
    float* psum = h + (size_t)BB * NN * DD;             // 1024
    float* psq  = psum + BB * DD;                       // 1024
    float* sP   = psq + BB * DD;                        // 1024
    float* cP   = sP + BB * DD;                         // 1024
    unsigned short* wgf = (unsigned short*)(cP + BB * DD);       // 3*16384 bf16
    unsigned short* tT  = wgf + LL * DD * DD;                    // B*D*N bf16 (8MB)
    unsigned short* A   = tT + (size_t)BB * DD * NN;             // B*N*N bf16 (64MB)

    prep_wg<<<(LL * DD * DD) / 256, 256, 0, stream>>>(Wg, wgf);
    gen_adj<<<BB * 64, 256, 0, stream>>>(inst, A, dinv);
    proj_kernel<<<(BB * NN * DD) / 256, 256, 0, stream>>>(inst, Wn, bn, h, sP, cP, psum, psq);

    for (int l = 0; l < LL; ++l) {
        lin_mfma<<<(BB * NN) / 32, 256, 0, stream>>>(
            h, wgf + (size_t)l * DD * DD, dinv, sP, cP, tT);
        agg_mfma<<<BB * (NN / 32), 256, 0, stream>>>(
            A, tT, dinv, bg + l * DD, sP, cP, h, psum, psq);
        stats_fin_kernel<<<(BB * DD + 255) / 256, 256, 0, stream>>>(
            psum, psq, ga, gw, gb, sP, cP);
    }
    apply_kernel<<<(BB * NN * DD / 4) / 256, 256, 0, stream>>>(h, sP, cP, out);
}